// Round 6
// baseline (645.038 us; speedup 1.0000x reference)
//
#include <hip/hip_runtime.h>

typedef __bf16 bf16x8 __attribute__((ext_vector_type(8)));
typedef float  f32x4  __attribute__((ext_vector_type(4)));
typedef int    v4i    __attribute__((ext_vector_type(4)));

#define LOG2E 1.4426950408889634f

__device__ __forceinline__ float fexp(float x){ return __builtin_amdgcn_exp2f(x * LOG2E); }
__device__ __forceinline__ float sigm(float x){ return __builtin_amdgcn_rcpf(1.0f + fexp(-x)); }
// tanh(x) = 2*sigm(2x)-1 ; exp2 overflow/underflow saturate correctly
__device__ __forceinline__ float ftanh(float x){
  float r = __builtin_amdgcn_rcpf(1.0f + __builtin_amdgcn_exp2f(-2.0f*LOG2E*x));
  return 2.0f*r - 1.0f;
}
__device__ __forceinline__ f32x4 MFMA(bf16x8 a, bf16x8 b, f32x4 c){
  return __builtin_amdgcn_mfma_f32_16x16x32_bf16(a, b, c, 0, 0, 0);
}
#define BC(w) __builtin_bit_cast(v4i, (w))

// One K-tile = ONE asm: 6 MFMAs, no compiler-scheduled instruction can land
// between them; trailing s_nop 3 covers the MFMA srcA/B multi-cycle read
// window (WAR) against compiler VALU scheduled right after. Weights B in AGPR.
#define GRP_A(LEAD, A_, KT_) asm volatile(LEAD                  \
    "v_mfma_f32_16x16x32_bf16 %0, %6, %7, %0\n\t"               \
    "v_mfma_f32_16x16x32_bf16 %1, %6, %8, %1\n\t"               \
    "v_mfma_f32_16x16x32_bf16 %2, %6, %9, %2\n\t"               \
    "v_mfma_f32_16x16x32_bf16 %3, %6, %10, %3\n\t"              \
    "v_mfma_f32_16x16x32_bf16 %4, %6, %11, %4\n\t"              \
    "v_mfma_f32_16x16x32_bf16 %5, %6, %12, %5\n\t"              \
    "s_nop 3"                                                   \
    : "+a"(acc0),"+a"(acc1),"+a"(acc2),"+a"(acc3),"+a"(acc4),"+a"(acc5) \
    : "v"(A_), "a"(awf[(KT_)]),"a"(awf[(KT_)+7]),"a"(awf[(KT_)+14]),    \
      "a"(awf[(KT_)+21]),"a"(awf[(KT_)+28]),"a"(awf[(KT_)+35]))

// LDS-weight K-tile: the 6 B ds_reads live INSIDE the asm ("=&v" temps) so
// the compiler never sees 48 regs of B pressure and the temps are WAR-safe
// by construction (LDS return >=37cyc after issue > read window).
#define GRP_L(A_, ADDR_) asm volatile(                          \
    "ds_read_b128 %6, %13\n\t"                                  \
    "ds_read_b128 %7, %13 offset:1024\n\t"                      \
    "ds_read_b128 %8, %13 offset:16384\n\t"                     \
    "ds_read_b128 %9, %13 offset:17408\n\t"                     \
    "ds_read_b128 %10, %13 offset:32768\n\t"                    \
    "ds_read_b128 %11, %13 offset:33792\n\t"                    \
    "s_waitcnt lgkmcnt(0)\n\t"                                  \
    "v_mfma_f32_16x16x32_bf16 %0, %12, %6, %0\n\t"              \
    "v_mfma_f32_16x16x32_bf16 %1, %12, %7, %1\n\t"              \
    "v_mfma_f32_16x16x32_bf16 %2, %12, %8, %2\n\t"              \
    "v_mfma_f32_16x16x32_bf16 %3, %12, %9, %3\n\t"              \
    "v_mfma_f32_16x16x32_bf16 %4, %12, %10, %4\n\t"             \
    "v_mfma_f32_16x16x32_bf16 %5, %12, %11, %5\n\t"             \
    "s_nop 3"                                                   \
    : "+a"(acc0),"+a"(acc1),"+a"(acc2),"+a"(acc3),"+a"(acc4),"+a"(acc5), \
      "=&v"(t0),"=&v"(t1),"=&v"(t2),"=&v"(t3),"=&v"(t4),"=&v"(t5)        \
    : "v"(A_), "v"(ADDR_))

// B=2048, T=128, D=32, H=256, S=39, PM=12
// 256 wg x 512 threads (8 waves), 8 batch rows per wg (rows 8-15 of all tiles
// stay zero; their acc rows are discarded). Wave w owns gate-cols
// {f,g,o} x [32w,32w+32). Weights: K-tiles 0..6 in AGPR (168) + acc (24) =
// 192 AGPR -> 64 arch VGPRs (structural: LDS fits only 2 wlds K-tile-sets).
__global__ void
__attribute__((amdgpu_flat_work_group_size(512,512), amdgpu_waves_per_eu(2,2)))
ealstm_kernel(
    const float* __restrict__ x,      const float* __restrict__ latlons,
    const float* __restrict__ yearly, const float* __restrict__ pm,
    const float* __restrict__ Wf_i, const float* __restrict__ Wf_h, const float* __restrict__ bf_h,
    const float* __restrict__ Wu,   const float* __restrict__ bu,
    const float* __restrict__ Wg_i, const float* __restrict__ Wg_h, const float* __restrict__ bg_h,
    const float* __restrict__ Wo_i, const float* __restrict__ Wo_h, const float* __restrict__ bo_h,
    const float* __restrict__ Wd0,  const float* __restrict__ bd0,
    const float* __restrict__ Wd1,  const float* __restrict__ bd1,
    float* __restrict__ out)
{
  // LDS: 16896 + 2560 + 98304 + 4096 = 121856 B (1 block/CU)
  __shared__ __align__(16) __bf16 hbuf[2][16*264];  // h, dbuf; stride 264
  __shared__ __align__(16) __bf16 xbuf[2][16*40];   // x_t, dbuf; stride 40
  __shared__ __align__(16) __bf16 wlds[2*48*512];   // frag = kk*48 + g*16 + nt (kk0: h K-tile7, kk1: x)
  __shared__ __align__(16) float  xs[16*64];        // [latlons|yearly|0], rows 8-15 zero

  const int tid  = threadIdx.x;
  const int w    = tid >> 6;
  const int lane = tid & 63;
  const int q    = lane >> 4;
  const int l    = lane & 15;
  const int wgb  = blockIdx.x * 8;

  const float* Wh[3] = {Wf_h, Wg_h, Wo_h};
  const float* Wi[3] = {Wf_i, Wg_i, Wo_i};
  const float* bH[3] = {bf_h, bg_h, bo_h};

  // ---------------- init: LDS fills ----------------
  for(int idx = tid; idx < 16*64; idx += 512){
    int m = idx >> 6, k = idx & 63;
    float v = 0.0f;
    if(m < 8){
      int b = wgb + m;
      if(k < 2) v = latlons[b*2 + k];
      else if(k < 39) v = yearly[b*37 + (k-2)];
    }
    xs[idx] = v;
  }
  for(int idx = tid; idx < 2*16*264; idx += 512) ((__bf16*)hbuf)[idx] = (__bf16)0.0f;
  { // xbuf rows 8-15 of both buffers: zero (never written again)
    int buf = tid >> 8, r = 8 + ((tid >> 5) & 7), c = tid & 31;
    xbuf[buf][r*40 + c] = (__bf16)0.0f;
  }
  if(tid < 256){ // t=0, rows 0-7
    int m = tid >> 5, k = tid & 31;
    xbuf[0][m*40 + k] = (__bf16)x[(size_t)(wgb + m)*4096 + k];
  }
  for(int grp = tid; grp < 2*48*64; grp += 512){
    int frag = grp >> 6, ln = grp & 63;
    int kk = frag / 48, f2 = frag % 48;
    int g = f2 >> 4, nt = f2 & 15;
    int q2 = ln >> 4, l2 = ln & 15;
    int cc = nt*16 + l2;
    const float* p = (kk == 0) ? (Wh[g] + cc*256 + 224 + q2*8)
                               : (Wi[g] + cc*32  + q2*8);
    bf16x8 v;
    #pragma unroll
    for(int j=0;j<8;j++) v[j] = (__bf16)p[j];
    *(bf16x8*)&wlds[frag*512 + ln*8] = v;
  }

  // ---------------- init: AGPR weight frags. f = (g*2+n)*7 + kt, kt=0..6 ----------------
  v4i awf[42];
  #pragma unroll
  for(int f = 0; f < 42; f++){
    int gn = f / 7, kt = f % 7;
    int g = gn >> 1, n = gn & 1;
    int cc = w*32 + n*16 + l;
    const float* p = Wh[g] + cc*256 + kt*32 + q*8;
    f32x4 v0 = *(const f32x4*)p;
    f32x4 v1 = *(const f32x4*)(p + 4);
    bf16x8 v;
    v[0]=(__bf16)v0[0]; v[1]=(__bf16)v0[1]; v[2]=(__bf16)v0[2]; v[3]=(__bf16)v0[3];
    v[4]=(__bf16)v1[0]; v[5]=(__bf16)v1[1]; v[6]=(__bf16)v1[2]; v[7]=(__bf16)v1[3];
    awf[f] = BC(v);
  }
  float bgn[6];
  #pragma unroll
  for(int gn=0; gn<6; gn++) bgn[gn] = bH[gn>>1][w*32 + (gn&1)*16 + l];

  const int  srcl = lane & 31;
  const bool lo   = lane < 32;
  const int  qq4  = (q & 1) * 4;                 // row base of the triples this thread owns
  const int  colw = w*32 + ((lane & 32) >> 1) + l; // col: lower half n=0, upper n=1
  const unsigned waddr0 = (unsigned)(unsigned long long)&wlds[(0*48 + w*2)*512 + lane*8];
  const unsigned waddr1 = (unsigned)(unsigned long long)&wlds[(1*48 + w*2)*512 + lane*8];

  __syncthreads();

  // ---------------- i_gate = sigmoid(x_s @ Wu^T + bu), redistributed ----------------
  f32x4 igv;
  {
    float bu0 = bu[w*32 + l], bu1 = bu[w*32 + 16 + l];
    f32x4 iga0 = {bu0,bu0,bu0,bu0};
    f32x4 iga1 = {bu1,bu1,bu1,bu1};
    #pragma unroll
    for(int kt=0; kt<2; kt++){
      bf16x8 a;
      const float* xr = &xs[l*64 + kt*32 + q*8];
      #pragma unroll
      for(int j=0;j<8;j++) a[j] = (__bf16)xr[j];
      #pragma unroll
      for(int n=0;n<2;n++){
        int cc = w*32 + n*16 + l;
        bf16x8 b;
        #pragma unroll
        for(int j=0;j<8;j++){
          int k = kt*32 + q*8 + j;
          b[j] = (__bf16)((k < 39) ? Wu[cc*39 + k] : 0.0f);
        }
        if(n == 0) iga0 = MFMA(a, b, iga0); else iga1 = MFMA(a, b, iga1);
      }
    }
    #pragma unroll
    for(int i=0;i<4;i++){
      float s0 = sigm(iga0[i]);
      float s1 = __shfl(sigm(iga1[i]), srcl);
      igv[i] = lo ? s0 : s1;
    }
  }

  f32x4 cst = {0.f, 0.f, 0.f, 0.f};

  // ---------------- recurrence: 128 steps, 1 barrier/step ----------------
#define LSTM_STEP(T_, CUR_)                                                     \
  {                                                                             \
    const int t = (T_);                                                         \
    /* stage x_{t+1} FIRST (before any MFMA is in flight), then fence so     */ \
    /* none of its VALU/VMEM writes can sink into the MFMA stream (WAR).     */ \
    if(w == 7 && lane < 32 && t < 127){                                         \
      int row = lane >> 2, c0 = (lane & 3) * 8;                                 \
      const float* xp = x + (size_t)(wgb + row)*4096 + (t+1)*32 + c0;           \
      f32x4 v0 = *(const f32x4*)xp;                                             \
      f32x4 v1 = *(const f32x4*)(xp + 4);                                       \
      bf16x8 v;                                                                 \
      v[0]=(__bf16)v0[0]; v[1]=(__bf16)v0[1]; v[2]=(__bf16)v0[2]; v[3]=(__bf16)v0[3]; \
      v[4]=(__bf16)v1[0]; v[5]=(__bf16)v1[1]; v[6]=(__bf16)v1[2]; v[7]=(__bf16)v1[3]; \
      *(bf16x8*)&xbuf[(CUR_) ^ 1][row*40 + c0] = v;                             \
    }                                                                           \
    asm volatile("" ::: "memory");                                              \
    f32x4 bc0 = {bgn[0],bgn[0],bgn[0],bgn[0]};                                  \
    f32x4 bc1 = {bgn[1],bgn[1],bgn[1],bgn[1]};                                  \
    f32x4 bc2 = {bgn[2],bgn[2],bgn[2],bgn[2]};                                  \
    f32x4 bc3 = {bgn[3],bgn[3],bgn[3],bgn[3]};                                  \
    f32x4 bc4 = {bgn[4],bgn[4],bgn[4],bgn[4]};                                  \
    f32x4 bc5 = {bgn[5],bgn[5],bgn[5],bgn[5]};                                  \
    v4i acc0 = BC(bc0), acc1 = BC(bc1), acc2 = BC(bc2);                         \
    v4i acc3 = BC(bc3), acc4 = BC(bc4), acc5 = BC(bc5);                         \
    v4i t0, t1, t2, t3, t4, t5;                                                 \
    const __bf16* hb = hbuf[CUR_];                                              \
    { v4i a = BC(*(const bf16x8*)&hb[l*264 + 0*32 + q*8]); GRP_A("s_nop 2\n\t", a, 0); } \
    { v4i a = BC(*(const bf16x8*)&hb[l*264 + 1*32 + q*8]); GRP_A("", a, 1); }   \
    { v4i a = BC(*(const bf16x8*)&hb[l*264 + 2*32 + q*8]); GRP_A("", a, 2); }   \
    { v4i a = BC(*(const bf16x8*)&hb[l*264 + 3*32 + q*8]); GRP_A("", a, 3); }   \
    { v4i a = BC(*(const bf16x8*)&hb[l*264 + 4*32 + q*8]); GRP_A("", a, 4); }   \
    { v4i a = BC(*(const bf16x8*)&hb[l*264 + 5*32 + q*8]); GRP_A("", a, 5); }   \
    { v4i a = BC(*(const bf16x8*)&hb[l*264 + 6*32 + q*8]); GRP_A("", a, 6); }   \
    { v4i a = BC(*(const bf16x8*)&hb[l*264 + 7*32 + q*8]); GRP_L(a, waddr0); }  \
    { v4i a = BC(*(const bf16x8*)&xbuf[CUR_][l*40 + q*8]); GRP_L(a, waddr1); }  \
    asm volatile("s_nop 7\n\ts_nop 7\n\ts_nop 7"                                \
      : "+a"(acc0),"+a"(acc1),"+a"(acc2),"+a"(acc3),"+a"(acc4),"+a"(acc5));     \
    f32x4 a0 = __builtin_bit_cast(f32x4, acc0);                                 \
    f32x4 a1 = __builtin_bit_cast(f32x4, acc1);                                 \
    f32x4 a2 = __builtin_bit_cast(f32x4, acc2);                                 \
    f32x4 a3 = __builtin_bit_cast(f32x4, acc3);                                 \
    f32x4 a4 = __builtin_bit_cast(f32x4, acc4);                                 \
    f32x4 a5 = __builtin_bit_cast(f32x4, acc5);                                 \
    _Pragma("unroll")                                                           \
    for(int i=0;i<4;i++){                                                       \
      float f1 = __shfl(a1[i], srcl);                                           \
      float g1 = __shfl(a3[i], srcl);                                           \
      float o1 = __shfl(a5[i], srcl);                                           \
      float fv = sigm (lo ? a0[i] : f1);                                        \
      float gv = ftanh(lo ? a2[i] : g1);                                        \
      float ov = sigm (lo ? a4[i] : o1);                                        \
      float cc = fv * cst[i] + igv[i] * gv;                                     \
      cst[i] = cc;                                                              \
      hbuf[(CUR_) ^ 1][(qq4 + i)*264 + colw] = (__bf16)(ov * ftanh(cc));        \
    }                                                                           \
    __syncthreads();                                                            \
  }

  #pragma unroll 1
  for(int tt = 0; tt < 64; tt++){
    LSTM_STEP(2*tt,     0)
    LSTM_STEP(2*tt + 1, 1)
  }
#undef LSTM_STEP

  // ---------------- head: z1 = [h_last, pm] @ Wd0^T + bd0 ; out = z1 @ Wd1^T + bd1 ----------------
  // h_last rows 0-7 in hbuf[0] (t=127 wrote buffer 0); rows 8-15 are zero.
  f32x4 hd[2];
  { f32x4 z4 = {0.f,0.f,0.f,0.f}; hd[0] = z4; hd[1] = z4; }
  #pragma unroll
  for(int kt=0; kt<8; kt++){
    bf16x8 a = *(const bf16x8*)&hbuf[0][l*264 + kt*32 + q*8];
    #pragma unroll
    for(int n=0;n<2;n++){
      int cc = w*32 + n*16 + l;
      const float* p = Wd0 + cc*268 + kt*32 + q*8;
      bf16x8 b;
      #pragma unroll
      for(int j=0;j<8;j++) b[j] = (__bf16)p[j];
      hd[n] = MFMA(a, b, hd[n]);
    }
  }
  { // K-tile 8: pm (k=256..267); only rows l<8 are real
    bf16x8 a;
    #pragma unroll
    for(int j=0;j<8;j++){
      int k2 = q*8 + j;
      a[j] = (__bf16)((l < 8 && k2 < 12) ? pm[(size_t)(wgb + l)*12 + k2] : 0.0f);
    }
    #pragma unroll
    for(int n=0;n<2;n++){
      int cc = w*32 + n*16 + l;
      bf16x8 b;
      #pragma unroll
      for(int j=0;j<8;j++){
        int k2 = q*8 + j;
        b[j] = (__bf16)((k2 < 12) ? Wd0[cc*268 + 256 + k2] : 0.0f);
      }
      hd[n] = MFMA(a, b, hd[n]);
    }
  }
  float* z1 = (float*)wlds;   // safe: wlds reads all precede the loop-final barrier
  #pragma unroll
  for(int n=0;n<2;n++){
    int cc = w*32 + n*16 + l;
    float bb = bd0[cc];
    #pragma unroll
    for(int i=0;i<4;i++) z1[(q*4 + i)*264 + cc] = hd[n][i] + bb;
  }
  __syncthreads();
  if(tid < 256){
    int row = tid >> 5, seg = tid & 31;   // rows 0-7 x 32 segments
    const float* zr = &z1[row*264 + seg*8];
    const float* wr = Wd1 + seg*8;
    float s = 0.0f;
    #pragma unroll
    for(int j=0;j<8;j++) s += zr[j] * wr[j];
    s += __shfl_xor(s, 1);
    s += __shfl_xor(s, 2);
    s += __shfl_xor(s, 4);
    s += __shfl_xor(s, 8);
    s += __shfl_xor(s, 16);
    if(seg == 0) out[wgb + row] = s + bd1[0];
  }
}

extern "C" void kernel_launch(void* const* d_in, const int* in_sizes, int n_in,
                              void* d_out, int out_size, void* d_ws, size_t ws_size,
                              hipStream_t stream) {
  const float* x       = (const float*)d_in[0];
  const float* latlons = (const float*)d_in[1];
  const float* yearly  = (const float*)d_in[2];
  const float* pm      = (const float*)d_in[3];
  const float* Wf_i    = (const float*)d_in[4];
  const float* Wf_h    = (const float*)d_in[5];
  const float* bf_h    = (const float*)d_in[6];
  const float* Wu      = (const float*)d_in[7];
  const float* bu      = (const float*)d_in[8];
  const float* Wg_i    = (const float*)d_in[9];
  const float* Wg_h    = (const float*)d_in[10];
  const float* bg_h    = (const float*)d_in[11];
  const float* Wo_i    = (const float*)d_in[12];
  const float* Wo_h    = (const float*)d_in[13];
  const float* bo_h    = (const float*)d_in[14];
  const float* Wd0     = (const float*)d_in[15];
  const float* bd0     = (const float*)d_in[16];
  const float* Wd1     = (const float*)d_in[17];
  const float* bd1     = (const float*)d_in[18];

  ealstm_kernel<<<dim3(256), dim3(512), 0, stream>>>(
      x, latlons, yearly, pm,
      Wf_i, Wf_h, bf_h, Wu, bu,
      Wg_i, Wg_h, bg_h, Wo_i, Wo_h, bo_h,
      Wd0, bd0, Wd1, bd1,
      (float*)d_out);
}

// Round 7
// 413.855 us; speedup vs baseline: 1.5586x; 1.5586x over previous
//
#include <hip/hip_runtime.h>

typedef __bf16 bf16x8 __attribute__((ext_vector_type(8)));
typedef float  f32x4  __attribute__((ext_vector_type(4)));
typedef int    v4i    __attribute__((ext_vector_type(4)));

#define LOG2E 1.4426950408889634f

__device__ __forceinline__ float fexp(float x){ return __builtin_amdgcn_exp2f(x * LOG2E); }
__device__ __forceinline__ float sigm(float x){ return __builtin_amdgcn_rcpf(1.0f + fexp(-x)); }
// tanh(x) = 2*sigm(2x)-1 ; exp2 over/underflow saturate correctly
__device__ __forceinline__ float ftanh(float x){
  float r = __builtin_amdgcn_rcpf(1.0f + __builtin_amdgcn_exp2f(-2.0f*LOG2E*x));
  return 2.0f*r - 1.0f;
}
__device__ __forceinline__ f32x4 MFMA(bf16x8 a, bf16x8 b, f32x4 c){
  return __builtin_amdgcn_mfma_f32_16x16x32_bf16(a, b, c, 0, 0, 0);
}
#define BC(w) __builtin_bit_cast(v4i, (w))

// R2/R3/R6 evidence: the backend splits the unified per-wave budget 50/50
// (arch/AGPR) whenever MFMA is present, and spills whatever exceeds either
// half. So: demand <=128 of EACH class by construction.
//   AGPR : weight K-tiles 0..4  = 30 frags = 120 regs  ("a" constraints)
//   arch : weight K-tiles 5..6  = 12 frags =  48 regs  ("v" constraints)
//          + accumulators in VGPRs ("+v": gfx950 MFMA C/D may be VGPR)
// One K-tile = ONE asm statement (6 MFMAs) so no compiler instruction can
// land inside; trailing s_nop 3 covers the MFMA srcA/B read window (WAR).
#define GRP_A(LEAD, A_, KT_) asm volatile(LEAD                  \
    "v_mfma_f32_16x16x32_bf16 %0, %6, %7, %0\n\t"               \
    "v_mfma_f32_16x16x32_bf16 %1, %6, %8, %1\n\t"               \
    "v_mfma_f32_16x16x32_bf16 %2, %6, %9, %2\n\t"               \
    "v_mfma_f32_16x16x32_bf16 %3, %6, %10, %3\n\t"              \
    "v_mfma_f32_16x16x32_bf16 %4, %6, %11, %4\n\t"              \
    "v_mfma_f32_16x16x32_bf16 %5, %6, %12, %5\n\t"              \
    "s_nop 3"                                                   \
    : "+v"(acc0),"+v"(acc1),"+v"(acc2),"+v"(acc3),"+v"(acc4),"+v"(acc5) \
    : "v"(A_), "a"(awf[(KT_)]),"a"(awf[(KT_)+5]),"a"(awf[(KT_)+10]),    \
      "a"(awf[(KT_)+15]),"a"(awf[(KT_)+20]),"a"(awf[(KT_)+25]))

#define GRP_V(A_, O_) asm volatile(                             \
    "v_mfma_f32_16x16x32_bf16 %0, %6, %7, %0\n\t"               \
    "v_mfma_f32_16x16x32_bf16 %1, %6, %8, %1\n\t"               \
    "v_mfma_f32_16x16x32_bf16 %2, %6, %9, %2\n\t"               \
    "v_mfma_f32_16x16x32_bf16 %3, %6, %10, %3\n\t"              \
    "v_mfma_f32_16x16x32_bf16 %4, %6, %11, %4\n\t"              \
    "v_mfma_f32_16x16x32_bf16 %5, %6, %12, %5\n\t"              \
    "s_nop 3"                                                   \
    : "+v"(acc0),"+v"(acc1),"+v"(acc2),"+v"(acc3),"+v"(acc4),"+v"(acc5) \
    : "v"(A_), "v"(wvf[(O_)]),"v"(wvf[(O_)+2]),"v"(wvf[(O_)+4]),        \
      "v"(wvf[(O_)+6]),"v"(wvf[(O_)+8]),"v"(wvf[(O_)+10]))

// LDS-weight half-tile: 3 ds_reads inside the asm ("=&v" temps, 12 regs peak).
// Temps are WAR-safe: LDS data returns >=37cyc after issue > MFMA read window.
#define GRP_L3(AC0, AC1, AC2, A_, ADDR_, O0, O1, O2) asm volatile(  \
    "ds_read_b128 %3, %7 offset:" O0 "\n\t"                     \
    "ds_read_b128 %4, %7 offset:" O1 "\n\t"                     \
    "ds_read_b128 %5, %7 offset:" O2 "\n\t"                     \
    "s_waitcnt lgkmcnt(0)\n\t"                                  \
    "v_mfma_f32_16x16x32_bf16 %0, %6, %3, %0\n\t"               \
    "v_mfma_f32_16x16x32_bf16 %1, %6, %4, %1\n\t"               \
    "v_mfma_f32_16x16x32_bf16 %2, %6, %5, %2\n\t"               \
    "s_nop 3"                                                   \
    : "+v"(AC0),"+v"(AC1),"+v"(AC2),                            \
      "=&v"(t0),"=&v"(t1),"=&v"(t2)                             \
    : "v"(A_), "v"(ADDR_))

// B=2048, T=128, D=32, H=256, S=39, PM=12
// 256 wg x 512 threads (8 waves), 8 batch rows per wg (tile rows 8-15 zero).
// Wave w owns gate-cols {f,g,o} x [32w,32w+32); gate math redistributed so
// upper 32 lanes handle the n=1 half (shfl), halving trans-VALU per thread.
__global__ void
__attribute__((amdgpu_flat_work_group_size(512,512), amdgpu_waves_per_eu(2,2)))
ealstm_kernel(
    const float* __restrict__ x,      const float* __restrict__ latlons,
    const float* __restrict__ yearly, const float* __restrict__ pm,
    const float* __restrict__ Wf_i, const float* __restrict__ Wf_h, const float* __restrict__ bf_h,
    const float* __restrict__ Wu,   const float* __restrict__ bu,
    const float* __restrict__ Wg_i, const float* __restrict__ Wg_h, const float* __restrict__ bg_h,
    const float* __restrict__ Wo_i, const float* __restrict__ Wo_h, const float* __restrict__ bo_h,
    const float* __restrict__ Wd0,  const float* __restrict__ bd0,
    const float* __restrict__ Wd1,  const float* __restrict__ bd1,
    float* __restrict__ out)
{
  // LDS: 16896 + 2560 + 98304 + 4096 = 121856 B (1 block/CU)
  __shared__ __align__(16) __bf16 hbuf[2][16*264];  // h, dbuf; stride 264
  __shared__ __align__(16) __bf16 xbuf[2][16*40];   // x_t, dbuf; stride 40
  __shared__ __align__(16) __bf16 wlds[2*48*512];   // frag = kk*48 + g*16 + nt (kk0: h K-tile7, kk1: x)
  __shared__ __align__(16) float  xs[16*64];        // [latlons|yearly|0], rows 8-15 zero

  const int tid  = threadIdx.x;
  const int w    = tid >> 6;
  const int lane = tid & 63;
  const int q    = lane >> 4;
  const int l    = lane & 15;
  const int wgb  = blockIdx.x * 8;

  const float* Wh[3] = {Wf_h, Wg_h, Wo_h};
  const float* Wi[3] = {Wf_i, Wg_i, Wo_i};
  const float* bH[3] = {bf_h, bg_h, bo_h};

  // ---------------- init: LDS fills ----------------
  for(int idx = tid; idx < 16*64; idx += 512){
    int m = idx >> 6, k = idx & 63;
    float v = 0.0f;
    if(m < 8){
      int b = wgb + m;
      if(k < 2) v = latlons[b*2 + k];
      else if(k < 39) v = yearly[b*37 + (k-2)];
    }
    xs[idx] = v;
  }
  for(int idx = tid; idx < 2*16*264; idx += 512) ((__bf16*)hbuf)[idx] = (__bf16)0.0f;
  { // xbuf rows 8-15 of both buffers: zero (never written again)
    int buf = tid >> 8, r = 8 + ((tid >> 5) & 7), c = tid & 31;
    xbuf[buf][r*40 + c] = (__bf16)0.0f;
  }
  if(tid < 256){ // t=0, rows 0-7
    int m = tid >> 5, k = tid & 31;
    xbuf[0][m*40 + k] = (__bf16)x[(size_t)(wgb + m)*4096 + k];
  }
  for(int grp = tid; grp < 2*48*64; grp += 512){
    int frag = grp >> 6, ln = grp & 63;
    int kk = frag / 48, f2 = frag % 48;
    int g = f2 >> 4, nt = f2 & 15;
    int q2 = ln >> 4, l2 = ln & 15;
    int cc = nt*16 + l2;
    const float* p = (kk == 0) ? (Wh[g] + cc*256 + 224 + q2*8)
                               : (Wi[g] + cc*32  + q2*8);
    bf16x8 v;
    #pragma unroll
    for(int j=0;j<8;j++) v[j] = (__bf16)p[j];
    *(bf16x8*)&wlds[frag*512 + ln*8] = v;
  }

  // ---------------- init: weight frags ----------------
  // AGPR: awf[gn*5+kt], kt=0..4.  arch: wvf[gn*2+(kt-5)], kt=5,6.  gn=g*2+n.
  v4i awf[30];
  v4i wvf[12];
  #pragma unroll
  for(int f = 0; f < 42; f++){
    int gn = f / 7, kt = f % 7;
    int g = gn >> 1, n = gn & 1;
    int cc = w*32 + n*16 + l;
    const float* p = Wh[g] + cc*256 + kt*32 + q*8;
    f32x4 v0 = *(const f32x4*)p;
    f32x4 v1 = *(const f32x4*)(p + 4);
    bf16x8 v;
    v[0]=(__bf16)v0[0]; v[1]=(__bf16)v0[1]; v[2]=(__bf16)v0[2]; v[3]=(__bf16)v0[3];
    v[4]=(__bf16)v1[0]; v[5]=(__bf16)v1[1]; v[6]=(__bf16)v1[2]; v[7]=(__bf16)v1[3];
    if(kt < 5) awf[gn*5 + kt] = BC(v);
    else       wvf[gn*2 + (kt-5)] = BC(v);
    if((f % 7) == 6) asm volatile("" ::: "memory");  // choke load batching (init spill guard)
  }
  float bgn[6];
  #pragma unroll
  for(int gn=0; gn<6; gn++) bgn[gn] = bH[gn>>1][w*32 + (gn&1)*16 + l];

  const int  srcl = lane & 31;
  const bool lo   = lane < 32;
  const int  qq4  = (q & 1) * 4;                   // row base of owned triples
  const int  colw = w*32 + ((lane & 32) >> 1) + l; // col: lower half n=0, upper n=1
  const unsigned waddr0 = (unsigned)(unsigned long long)&wlds[(0*48 + w*2)*512 + lane*8];
  const unsigned waddr1 = (unsigned)(unsigned long long)&wlds[(1*48 + w*2)*512 + lane*8];

  __syncthreads();

  // ---------------- i_gate = sigmoid(x_s @ Wu^T + bu), redistributed ----------------
  f32x4 igv;
  {
    float bu0 = bu[w*32 + l], bu1 = bu[w*32 + 16 + l];
    f32x4 iga0 = {bu0,bu0,bu0,bu0};
    f32x4 iga1 = {bu1,bu1,bu1,bu1};
    #pragma unroll
    for(int kt=0; kt<2; kt++){
      bf16x8 a;
      const float* xr = &xs[l*64 + kt*32 + q*8];
      #pragma unroll
      for(int j=0;j<8;j++) a[j] = (__bf16)xr[j];
      #pragma unroll
      for(int n=0;n<2;n++){
        int cc = w*32 + n*16 + l;
        bf16x8 b;
        #pragma unroll
        for(int j=0;j<8;j++){
          int k = kt*32 + q*8 + j;
          b[j] = (__bf16)((k < 39) ? Wu[cc*39 + k] : 0.0f);
        }
        if(n == 0) iga0 = MFMA(a, b, iga0); else iga1 = MFMA(a, b, iga1);
      }
    }
    #pragma unroll
    for(int i=0;i<4;i++){
      float s0 = sigm(iga0[i]);
      float s1 = __shfl(sigm(iga1[i]), srcl);
      igv[i] = lo ? s0 : s1;
    }
  }

  f32x4 cst = {0.f, 0.f, 0.f, 0.f};

  // ---------------- recurrence: 128 steps, 1 barrier/step ----------------
#define LSTM_STEP(T_, CUR_)                                                     \
  {                                                                             \
    const int t = (T_);                                                         \
    /* stage x_{t+1} first, then fence so its writes can't sink into MFMAs */   \
    if(w == 7 && lane < 32 && t < 127){                                         \
      int row = lane >> 2, c0 = (lane & 3) * 8;                                 \
      const float* xp = x + (size_t)(wgb + row)*4096 + (t+1)*32 + c0;           \
      f32x4 v0 = *(const f32x4*)xp;                                             \
      f32x4 v1 = *(const f32x4*)(xp + 4);                                       \
      bf16x8 v;                                                                 \
      v[0]=(__bf16)v0[0]; v[1]=(__bf16)v0[1]; v[2]=(__bf16)v0[2]; v[3]=(__bf16)v0[3]; \
      v[4]=(__bf16)v1[0]; v[5]=(__bf16)v1[1]; v[6]=(__bf16)v1[2]; v[7]=(__bf16)v1[3]; \
      *(bf16x8*)&xbuf[(CUR_) ^ 1][row*40 + c0] = v;                             \
    }                                                                           \
    asm volatile("" ::: "memory");                                              \
    f32x4 bc0 = {bgn[0],bgn[0],bgn[0],bgn[0]};                                  \
    f32x4 bc1 = {bgn[1],bgn[1],bgn[1],bgn[1]};                                  \
    f32x4 bc2 = {bgn[2],bgn[2],bgn[2],bgn[2]};                                  \
    f32x4 bc3 = {bgn[3],bgn[3],bgn[3],bgn[3]};                                  \
    f32x4 bc4 = {bgn[4],bgn[4],bgn[4],bgn[4]};                                  \
    f32x4 bc5 = {bgn[5],bgn[5],bgn[5],bgn[5]};                                  \
    v4i acc0 = BC(bc0), acc1 = BC(bc1), acc2 = BC(bc2);                         \
    v4i acc3 = BC(bc3), acc4 = BC(bc4), acc5 = BC(bc5);                         \
    v4i t0, t1, t2;                                                             \
    const __bf16* hb = hbuf[CUR_];                                              \
    { v4i a = BC(*(const bf16x8*)&hb[l*264 + 0*32 + q*8]); GRP_A("s_nop 3\n\t", a, 0); } \
    { v4i a = BC(*(const bf16x8*)&hb[l*264 + 1*32 + q*8]); GRP_A("", a, 1); }   \
    { v4i a = BC(*(const bf16x8*)&hb[l*264 + 2*32 + q*8]); GRP_A("", a, 2); }   \
    { v4i a = BC(*(const bf16x8*)&hb[l*264 + 3*32 + q*8]); GRP_A("", a, 3); }   \
    { v4i a = BC(*(const bf16x8*)&hb[l*264 + 4*32 + q*8]); GRP_A("", a, 4); }   \
    { v4i a = BC(*(const bf16x8*)&hb[l*264 + 5*32 + q*8]); GRP_V(a, 0); }       \
    { v4i a = BC(*(const bf16x8*)&hb[l*264 + 6*32 + q*8]); GRP_V(a, 1); }       \
    { v4i a = BC(*(const bf16x8*)&hb[l*264 + 7*32 + q*8]);                      \
      GRP_L3(acc0, acc2, acc4, a, waddr0, "0", "16384", "32768");               \
      GRP_L3(acc1, acc3, acc5, a, waddr0, "1024", "17408", "33792"); }          \
    { v4i a = BC(*(const bf16x8*)&xbuf[CUR_][l*40 + q*8]);                      \
      GRP_L3(acc0, acc2, acc4, a, waddr1, "0", "16384", "32768");               \
      GRP_L3(acc1, acc3, acc5, a, waddr1, "1024", "17408", "33792"); }          \
    asm volatile("s_nop 7\n\ts_nop 7\n\ts_nop 7"                                \
      : "+v"(acc0),"+v"(acc1),"+v"(acc2),"+v"(acc3),"+v"(acc4),"+v"(acc5));     \
    f32x4 a0 = __builtin_bit_cast(f32x4, acc0);                                 \
    f32x4 a1 = __builtin_bit_cast(f32x4, acc1);                                 \
    f32x4 a2 = __builtin_bit_cast(f32x4, acc2);                                 \
    f32x4 a3 = __builtin_bit_cast(f32x4, acc3);                                 \
    f32x4 a4 = __builtin_bit_cast(f32x4, acc4);                                 \
    f32x4 a5 = __builtin_bit_cast(f32x4, acc5);                                 \
    _Pragma("unroll")                                                           \
    for(int i=0;i<4;i++){                                                       \
      float f1 = __shfl(a1[i], srcl);                                           \
      float g1 = __shfl(a3[i], srcl);                                           \
      float o1 = __shfl(a5[i], srcl);                                           \
      float fv = sigm (lo ? a0[i] : f1);                                        \
      float gv = ftanh(lo ? a2[i] : g1);                                        \
      float ov = sigm (lo ? a4[i] : o1);                                        \
      float cc = fv * cst[i] + igv[i] * gv;                                     \
      cst[i] = cc;                                                              \
      hbuf[(CUR_) ^ 1][(qq4 + i)*264 + colw] = (__bf16)(ov * ftanh(cc));        \
    }                                                                           \
    __syncthreads();                                                            \
  }

  #pragma unroll 1
  for(int tt = 0; tt < 64; tt++){
    LSTM_STEP(2*tt,     0)
    LSTM_STEP(2*tt + 1, 1)
  }
#undef LSTM_STEP

  // ---------------- head: z1 = [h_last, pm] @ Wd0^T + bd0 ; out = z1 @ Wd1^T + bd1 ----------------
  // h_last rows 0-7 in hbuf[0]; rows 8-15 zero.
  f32x4 hd[2];
  { f32x4 z4 = {0.f,0.f,0.f,0.f}; hd[0] = z4; hd[1] = z4; }
  #pragma unroll 2
  for(int kt=0; kt<8; kt++){
    bf16x8 a = *(const bf16x8*)&hbuf[0][l*264 + kt*32 + q*8];
    #pragma unroll
    for(int n=0;n<2;n++){
      int cc = w*32 + n*16 + l;
      const float* p = Wd0 + cc*268 + kt*32 + q*8;
      bf16x8 b;
      #pragma unroll
      for(int j=0;j<8;j++) b[j] = (__bf16)p[j];
      hd[n] = MFMA(a, b, hd[n]);
    }
  }
  { // K-tile 8: pm (k=256..267); only rows l<8 are real
    bf16x8 a;
    #pragma unroll
    for(int j=0;j<8;j++){
      int k2 = q*8 + j;
      a[j] = (__bf16)((l < 8 && k2 < 12) ? pm[(size_t)(wgb + l)*12 + k2] : 0.0f);
    }
    #pragma unroll
    for(int n=0;n<2;n++){
      int cc = w*32 + n*16 + l;
      bf16x8 b;
      #pragma unroll
      for(int j=0;j<8;j++){
        int k2 = q*8 + j;
        b[j] = (__bf16)((k2 < 12) ? Wd0[cc*268 + 256 + k2] : 0.0f);
      }
      hd[n] = MFMA(a, b, hd[n]);
    }
  }
  float* z1 = (float*)wlds;   // safe: wlds reads all precede the loop-final barrier
  #pragma unroll
  for(int n=0;n<2;n++){
    int cc = w*32 + n*16 + l;
    float bb = bd0[cc];
    #pragma unroll
    for(int i=0;i<4;i++) z1[(q*4 + i)*264 + cc] = hd[n][i] + bb;
  }
  __syncthreads();
  if(tid < 256){
    int row = tid >> 5, seg = tid & 31;   // rows 0-7 x 32 segments
    const float* zr = &z1[row*264 + seg*8];
    const float* wr = Wd1 + seg*8;
    float s = 0.0f;
    #pragma unroll
    for(int j=0;j<8;j++) s += zr[j] * wr[j];
    s += __shfl_xor(s, 1);
    s += __shfl_xor(s, 2);
    s += __shfl_xor(s, 4);
    s += __shfl_xor(s, 8);
    s += __shfl_xor(s, 16);
    if(seg == 0) out[wgb + row] = s + bd1[0];
  }
}

extern "C" void kernel_launch(void* const* d_in, const int* in_sizes, int n_in,
                              void* d_out, int out_size, void* d_ws, size_t ws_size,
                              hipStream_t stream) {
  const float* x       = (const float*)d_in[0];
  const float* latlons = (const float*)d_in[1];
  const float* yearly  = (const float*)d_in[2];
  const float* pm      = (const float*)d_in[3];
  const float* Wf_i    = (const float*)d_in[4];
  const float* Wf_h    = (const float*)d_in[5];
  const float* bf_h    = (const float*)d_in[6];
  const float* Wu      = (const float*)d_in[7];
  const float* bu      = (const float*)d_in[8];
  const float* Wg_i    = (const float*)d_in[9];
  const float* Wg_h    = (const float*)d_in[10];
  const float* bg_h    = (const float*)d_in[11];
  const float* Wo_i    = (const float*)d_in[12];
  const float* Wo_h    = (const float*)d_in[13];
  const float* bo_h    = (const float*)d_in[14];
  const float* Wd0     = (const float*)d_in[15];
  const float* bd0     = (const float*)d_in[16];
  const float* Wd1     = (const float*)d_in[17];
  const float* bd1     = (const float*)d_in[18];

  ealstm_kernel<<<dim3(256), dim3(512), 0, stream>>>(
      x, latlons, yearly, pm,
      Wf_i, Wf_h, bf_h, Wu, bu,
      Wg_i, Wg_h, bg_h, Wo_i, Wo_h, bo_h,
      Wd0, bd0, Wd1, bd1,
      (float*)d_out);
}

// Round 8
// 353.966 us; speedup vs baseline: 1.8223x; 1.1692x over previous
//
#include <hip/hip_runtime.h>

typedef __bf16 bf16x8 __attribute__((ext_vector_type(8)));
typedef float  f32x4  __attribute__((ext_vector_type(4)));
typedef int    v4i    __attribute__((ext_vector_type(4)));

#define LOG2E 1.4426950408889634f

__device__ __forceinline__ float fexp(float x){ return __builtin_amdgcn_exp2f(x * LOG2E); }
__device__ __forceinline__ float sigm(float x){ return __builtin_amdgcn_rcpf(1.0f + fexp(-x)); }
// tanh(x) = 2*sigm(2x)-1 ; exp2 over/underflow saturate correctly
__device__ __forceinline__ float ftanh(float x){
  float r = __builtin_amdgcn_rcpf(1.0f + __builtin_amdgcn_exp2f(-2.0f*LOG2E*x));
  return 2.0f*r - 1.0f;
}
__device__ __forceinline__ f32x4 MFMA(bf16x8 a, bf16x8 b, f32x4 c){
  return __builtin_amdgcn_mfma_f32_16x16x32_bf16(a, b, c, 0, 0, 0);
}
#define BC(w) __builtin_bit_cast(v4i, (w))

// Budget discipline (R2/R3/R6/R7): <=128 of EACH register class.
//   AGPR: 30 weight frags (K-tiles 0..4) = 120, born class-a via "=a" tie at def.
//   arch: 12 weight frags (K-tiles 5..6) = 48 + accs 24 + loop state ~50.
#define GRP_A(LEAD, A_, KT_) asm volatile(LEAD                  \
    "v_mfma_f32_16x16x32_bf16 %0, %6, %7, %0\n\t"               \
    "v_mfma_f32_16x16x32_bf16 %1, %6, %8, %1\n\t"               \
    "v_mfma_f32_16x16x32_bf16 %2, %6, %9, %2\n\t"               \
    "v_mfma_f32_16x16x32_bf16 %3, %6, %10, %3\n\t"              \
    "v_mfma_f32_16x16x32_bf16 %4, %6, %11, %4\n\t"              \
    "v_mfma_f32_16x16x32_bf16 %5, %6, %12, %5\n\t"              \
    "s_nop 3"                                                   \
    : "+v"(acc0),"+v"(acc1),"+v"(acc2),"+v"(acc3),"+v"(acc4),"+v"(acc5) \
    : "v"(A_), "a"(awf[(KT_)]),"a"(awf[(KT_)+5]),"a"(awf[(KT_)+10]),    \
      "a"(awf[(KT_)+15]),"a"(awf[(KT_)+20]),"a"(awf[(KT_)+25]))

#define GRP_V(A_, O_) asm volatile(                             \
    "v_mfma_f32_16x16x32_bf16 %0, %6, %7, %0\n\t"               \
    "v_mfma_f32_16x16x32_bf16 %1, %6, %8, %1\n\t"               \
    "v_mfma_f32_16x16x32_bf16 %2, %6, %9, %2\n\t"               \
    "v_mfma_f32_16x16x32_bf16 %3, %6, %10, %3\n\t"              \
    "v_mfma_f32_16x16x32_bf16 %4, %6, %11, %4\n\t"              \
    "v_mfma_f32_16x16x32_bf16 %5, %6, %12, %5\n\t"              \
    "s_nop 3"                                                   \
    : "+v"(acc0),"+v"(acc1),"+v"(acc2),"+v"(acc3),"+v"(acc4),"+v"(acc5) \
    : "v"(A_), "v"(wvf[(O_)]),"v"(wvf[(O_)+2]),"v"(wvf[(O_)+4]),        \
      "v"(wvf[(O_)+6]),"v"(wvf[(O_)+8]),"v"(wvf[(O_)+10]))

// h K-tile 7 + x K-tile in ONE asm: 12 ds_reads, only 2 lgkm waits exposed.
// Temps WAR-safe by construction (LDS writeback >=37cyc after issue > MFMA
// srcB read window; second-batch reads issue >=10cyc after last consumer).
#define GRP_LX(A7_, AX_) asm volatile(                          \
    "ds_read_b128 %6, %14\n\t"                                  \
    "ds_read_b128 %7, %14 offset:1024\n\t"                      \
    "ds_read_b128 %8, %14 offset:16384\n\t"                     \
    "ds_read_b128 %9, %14 offset:17408\n\t"                     \
    "ds_read_b128 %10, %14 offset:32768\n\t"                    \
    "ds_read_b128 %11, %14 offset:33792\n\t"                    \
    "s_waitcnt lgkmcnt(0)\n\t"                                  \
    "v_mfma_f32_16x16x32_bf16 %0, %12, %6, %0\n\t"              \
    "v_mfma_f32_16x16x32_bf16 %1, %12, %7, %1\n\t"              \
    "v_mfma_f32_16x16x32_bf16 %2, %12, %8, %2\n\t"              \
    "v_mfma_f32_16x16x32_bf16 %3, %12, %9, %3\n\t"              \
    "v_mfma_f32_16x16x32_bf16 %4, %12, %10, %4\n\t"             \
    "v_mfma_f32_16x16x32_bf16 %5, %12, %11, %5\n\t"             \
    "ds_read_b128 %6, %15\n\t"                                  \
    "ds_read_b128 %7, %15 offset:1024\n\t"                      \
    "ds_read_b128 %8, %15 offset:16384\n\t"                     \
    "ds_read_b128 %9, %15 offset:17408\n\t"                     \
    "ds_read_b128 %10, %15 offset:32768\n\t"                    \
    "ds_read_b128 %11, %15 offset:33792\n\t"                    \
    "s_waitcnt lgkmcnt(0)\n\t"                                  \
    "v_mfma_f32_16x16x32_bf16 %0, %13, %6, %0\n\t"              \
    "v_mfma_f32_16x16x32_bf16 %1, %13, %7, %1\n\t"              \
    "v_mfma_f32_16x16x32_bf16 %2, %13, %8, %2\n\t"              \
    "v_mfma_f32_16x16x32_bf16 %3, %13, %9, %3\n\t"              \
    "v_mfma_f32_16x16x32_bf16 %4, %13, %10, %4\n\t"             \
    "v_mfma_f32_16x16x32_bf16 %5, %13, %11, %5\n\t"             \
    "s_nop 3"                                                   \
    : "+v"(acc0),"+v"(acc1),"+v"(acc2),"+v"(acc3),"+v"(acc4),"+v"(acc5), \
      "=&v"(t0),"=&v"(t1),"=&v"(t2),"=&v"(t3),"=&v"(t4),"=&v"(t5)        \
    : "v"(A7_), "v"(AX_), "v"(waddr0), "v"(waddr1))

// Raw workgroup barrier: drain LDS (h/x tile visibility) but NOT vmcnt, so
// wave 7's x prefetch stays in flight across steps (__syncthreads would
// emit s_waitcnt vmcnt(0) and serialize the HBM load into every barrier).
#define BARRIER() asm volatile("s_waitcnt lgkmcnt(0)\n\ts_barrier" ::: "memory")

// B=2048, T=128, D=32, H=256, S=39, PM=12
// 256 wg x 512 threads (8 waves), 8 batch rows per wg (tile rows 8-15 zero).
// Wave w owns gate-cols {f,g,o} x [32w,32w+32); gate math redistributed so
// upper 32 lanes handle the n=1 half (shfl).
__global__ void
__attribute__((amdgpu_flat_work_group_size(512,512), amdgpu_waves_per_eu(2,2)))
ealstm_kernel(
    const float* __restrict__ x,      const float* __restrict__ latlons,
    const float* __restrict__ yearly, const float* __restrict__ pm,
    const float* __restrict__ Wf_i, const float* __restrict__ Wf_h, const float* __restrict__ bf_h,
    const float* __restrict__ Wu,   const float* __restrict__ bu,
    const float* __restrict__ Wg_i, const float* __restrict__ Wg_h, const float* __restrict__ bg_h,
    const float* __restrict__ Wo_i, const float* __restrict__ Wo_h, const float* __restrict__ bo_h,
    const float* __restrict__ Wd0,  const float* __restrict__ bd0,
    const float* __restrict__ Wd1,  const float* __restrict__ bd1,
    float* __restrict__ out)
{
  // LDS: 16384 + 2560 + 98304 + 4096 = 121344 B (1 block/CU)
  // hbuf kt-major: [buf][kt(8)][m(16)][k(32)] bf16 -> lane(l,q) A-read addr/16B
  // = kt*64 + 4l + q : 64 consecutive 16B chunks = conflict-free ds_read_b128.
  __shared__ __align__(16) __bf16 hbuf[2][4096];
  __shared__ __align__(16) __bf16 xbuf[2][16*40];   // stride 40 (coprime) per R4
  __shared__ __align__(16) __bf16 wlds[2*48*512];   // frag = kk*48 + g*16 + nt
  __shared__ __align__(16) float  xs[16*64];

  const int tid  = threadIdx.x;
  const int w    = tid >> 6;
  const int lane = tid & 63;
  const int q    = lane >> 4;
  const int l    = lane & 15;
  const int wgb  = blockIdx.x * 8;

  const float* Wh[3] = {Wf_h, Wg_h, Wo_h};
  const float* Wi[3] = {Wf_i, Wg_i, Wo_i};

  // ---------------- init: LDS fills ----------------
  for(int idx = tid; idx < 16*64; idx += 512){
    int m = idx >> 6, k = idx & 63;
    float v = 0.0f;
    if(m < 8){
      int b = wgb + m;
      if(k < 2) v = latlons[b*2 + k];
      else if(k < 39) v = yearly[b*37 + (k-2)];
    }
    xs[idx] = v;
  }
  for(int idx = tid; idx < 2*4096; idx += 512) ((__bf16*)hbuf)[idx] = (__bf16)0.0f;
  { // xbuf rows 8-15 of both buffers: zero
    int buf = tid >> 8, r = 8 + ((tid >> 5) & 7), c = tid & 31;
    xbuf[buf][r*40 + c] = (__bf16)0.0f;
  }
  if(tid < 256){ // t=0, rows 0-7
    int m = tid >> 5, k = tid & 31;
    xbuf[0][m*40 + k] = (__bf16)x[(size_t)(wgb + m)*4096 + k];
  }
  for(int grp = tid; grp < 2*48*64; grp += 512){
    int frag = grp >> 6, ln = grp & 63;
    int kk = frag / 48, f2 = frag % 48;
    int g = f2 >> 4, nt = f2 & 15;
    int q2 = ln >> 4, l2 = ln & 15;
    int cc = nt*16 + l2;
    const float* p = (kk == 0) ? (Wh[g] + cc*256 + 224 + q2*8)
                               : (Wi[g] + cc*32  + q2*8);
    bf16x8 v;
    #pragma unroll
    for(int j=0;j<8;j++) v[j] = (__bf16)p[j];
    *(bf16x8*)&wlds[frag*512 + ln*8] = v;
  }

  const int  srcl = lane & 31;
  const bool lo   = lane < 32;
  const int  qq4  = (q & 1) * 4;                   // row base of owned triples
  const int  colw = w*32 + ((lane & 32) >> 1) + l; // col: lower n=0, upper n=1
  // h-write base in kt-major layout
  const int  hwb  = (colw >> 5)*512 + qq4*32 + ((colw >> 3) & 3)*8 + (colw & 7);
  const unsigned waddr0 = (unsigned)(unsigned long long)&wlds[(0*48 + w*2)*512 + lane*8];
  const unsigned waddr1 = waddr0 + 49152u;
  // per-thread (post-redistribution) gate biases: 3 regs instead of 6
  const float b3f = bf_h[colw], b3g = bg_h[colw], b3o = bo_h[colw];

  __syncthreads();

  // ---------------- i_gate = sigmoid(x_s @ Wu^T + bu), redistributed ----------------
  f32x4 igv;
  {
    float bu0 = bu[w*32 + l], bu1 = bu[w*32 + 16 + l];
    f32x4 iga0 = {bu0,bu0,bu0,bu0};
    f32x4 iga1 = {bu1,bu1,bu1,bu1};
    #pragma unroll
    for(int kt=0; kt<2; kt++){
      bf16x8 a;
      const float* xr = &xs[l*64 + kt*32 + q*8];
      #pragma unroll
      for(int j=0;j<8;j++) a[j] = (__bf16)xr[j];
      #pragma unroll
      for(int n=0;n<2;n++){
        int cc = w*32 + n*16 + l;
        bf16x8 b;
        #pragma unroll
        for(int j=0;j<8;j++){
          int k = kt*32 + q*8 + j;
          b[j] = (__bf16)((k < 39) ? Wu[cc*39 + k] : 0.0f);
        }
        if(n == 0) iga0 = MFMA(a, b, iga0); else iga1 = MFMA(a, b, iga1);
      }
    }
    #pragma unroll
    for(int i=0;i<4;i++){
      float s0 = sigm(iga0[i]);
      float s1 = __shfl(sigm(iga1[i]), srcl);
      igv[i] = lo ? s0 : s1;
    }
  }

  // ---------------- weight frags LAST (minimal live-across pressure) ----------
  // arch: wvf[gn*2+(kt-5)], kt=5,6.
  v4i wvf[12];
  #pragma unroll
  for(int f = 0; f < 12; f++){
    int gn = f >> 1, kt = 5 + (f & 1);
    int g = gn >> 1, n = gn & 1;
    int cc = w*32 + n*16 + l;
    const float* p = Wh[g] + cc*256 + kt*32 + q*8;
    f32x4 v0 = *(const f32x4*)p;
    f32x4 v1 = *(const f32x4*)(p + 4);
    bf16x8 v;
    v[0]=(__bf16)v0[0]; v[1]=(__bf16)v0[1]; v[2]=(__bf16)v0[2]; v[3]=(__bf16)v0[3];
    v[4]=(__bf16)v1[0]; v[5]=(__bf16)v1[1]; v[6]=(__bf16)v1[2]; v[7]=(__bf16)v1[3];
    wvf[f] = BC(v);
    if((f & 3) == 3) asm volatile("" ::: "memory");  // choke load batching
  }
  // AGPR: awf[gn*5+kt], kt=0..4 — born class-a at def ("=a" tie) so the live
  // range never occupies arch VGPRs (R7's spill: generic def, class-a use).
  v4i awf[30];
  #pragma unroll
  for(int f = 0; f < 30; f++){
    int gn = f / 5, kt = f % 5;
    int g = gn >> 1, n = gn & 1;
    int cc = w*32 + n*16 + l;
    const float* p = Wh[g] + cc*256 + kt*32 + q*8;
    f32x4 v0 = *(const f32x4*)p;
    f32x4 v1 = *(const f32x4*)(p + 4);
    bf16x8 v;
    v[0]=(__bf16)v0[0]; v[1]=(__bf16)v0[1]; v[2]=(__bf16)v0[2]; v[3]=(__bf16)v0[3];
    v[4]=(__bf16)v1[0]; v[5]=(__bf16)v1[1]; v[6]=(__bf16)v1[2]; v[7]=(__bf16)v1[3];
    asm("" : "=a"(awf[f]) : "0"(BC(v)));
    if((f % 5) == 4) asm volatile("" ::: "memory");  // choke load batching
  }

  f32x4 cst = {0.f, 0.f, 0.f, 0.f};

  // x prefetch state (wave 7, lanes 0-31): pv holds x_{t+1} at step t entry.
  const int xri = (lane >> 2)*40 + (lane & 3)*8;   // xbuf store index
  const float* xbase = x + (size_t)(wgb + (lane >> 2))*4096 + (lane & 3)*8;
  f32x4 pv0 = {0.f,0.f,0.f,0.f}, pv1 = {0.f,0.f,0.f,0.f};
  if(w == 7 && lane < 32){
    pv0 = *(const f32x4*)(xbase + 32);
    pv1 = *(const f32x4*)(xbase + 36);
  }
  asm volatile("" ::: "memory");

  // ---------------- recurrence: 128 steps, 1 raw barrier/step ----------------
#define LSTM_STEP(T_, CUR_)                                                     \
  {                                                                             \
    /* wave7: store x_{t+1} (loaded one step ago -> latency hidden), then   */  \
    /* issue load of x_{t+2}; BARRIER does not drain vmcnt.                 */  \
    if(w == 7 && lane < 32){                                                    \
      if((T_) < 127){                                                           \
        bf16x8 v;                                                               \
        v[0]=(__bf16)pv0[0]; v[1]=(__bf16)pv0[1]; v[2]=(__bf16)pv0[2]; v[3]=(__bf16)pv0[3]; \
        v[4]=(__bf16)pv1[0]; v[5]=(__bf16)pv1[1]; v[6]=(__bf16)pv1[2]; v[7]=(__bf16)pv1[3]; \
        *(bf16x8*)&xbuf[(CUR_) ^ 1][xri] = v;                                   \
      }                                                                         \
      if((T_) < 126){                                                           \
        pv0 = *(const f32x4*)(xbase + ((T_)+2)*32);                             \
        pv1 = *(const f32x4*)(xbase + ((T_)+2)*32 + 4);                         \
      }                                                                         \
    }                                                                           \
    asm volatile("" ::: "memory");                                              \
    f32x4 z4 = {0.f,0.f,0.f,0.f};                                               \
    v4i acc0 = BC(z4), acc1 = BC(z4), acc2 = BC(z4);                            \
    v4i acc3 = BC(z4), acc4 = BC(z4), acc5 = BC(z4);                            \
    v4i t0, t1, t2, t3, t4, t5;                                                 \
    const __bf16* hb = hbuf[CUR_];                                              \
    { v4i a = BC(*(const bf16x8*)&hb[0*512 + l*32 + q*8]); GRP_A("s_nop 3\n\t", a, 0); } \
    { v4i a = BC(*(const bf16x8*)&hb[1*512 + l*32 + q*8]); GRP_A("", a, 1); }   \
    { v4i a = BC(*(const bf16x8*)&hb[2*512 + l*32 + q*8]); GRP_A("", a, 2); }   \
    { v4i a = BC(*(const bf16x8*)&hb[3*512 + l*32 + q*8]); GRP_A("", a, 3); }   \
    { v4i a = BC(*(const bf16x8*)&hb[4*512 + l*32 + q*8]); GRP_A("", a, 4); }   \
    { v4i a = BC(*(const bf16x8*)&hb[5*512 + l*32 + q*8]); GRP_V(a, 0); }       \
    { v4i a = BC(*(const bf16x8*)&hb[6*512 + l*32 + q*8]); GRP_V(a, 1); }       \
    { v4i a7 = BC(*(const bf16x8*)&hb[7*512 + l*32 + q*8]);                     \
      v4i ax = BC(*(const bf16x8*)&xbuf[CUR_][l*40 + q*8]);                     \
      GRP_LX(a7, ax); }                                                         \
    asm volatile("s_nop 7\n\ts_nop 7\n\ts_nop 7"                                \
      : "+v"(acc0),"+v"(acc1),"+v"(acc2),"+v"(acc3),"+v"(acc4),"+v"(acc5));     \
    f32x4 a0 = __builtin_bit_cast(f32x4, acc0);                                 \
    f32x4 a1 = __builtin_bit_cast(f32x4, acc1);                                 \
    f32x4 a2 = __builtin_bit_cast(f32x4, acc2);                                 \
    f32x4 a3 = __builtin_bit_cast(f32x4, acc3);                                 \
    f32x4 a4 = __builtin_bit_cast(f32x4, acc4);                                 \
    f32x4 a5 = __builtin_bit_cast(f32x4, acc5);                                 \
    _Pragma("unroll")                                                           \
    for(int i=0;i<4;i++){                                                       \
      float f1 = __shfl(a1[i], srcl);                                           \
      float g1 = __shfl(a3[i], srcl);                                           \
      float o1 = __shfl(a5[i], srcl);                                           \
      float fv = sigm ((lo ? a0[i] : f1) + b3f);                                \
      float gv = ftanh((lo ? a2[i] : g1) + b3g);                                \
      float ov = sigm ((lo ? a4[i] : o1) + b3o);                                \
      float cc = fv * cst[i] + igv[i] * gv;                                     \
      cst[i] = cc;                                                              \
      hbuf[(CUR_) ^ 1][hwb + i*32] = (__bf16)(ov * ftanh(cc));                  \
    }                                                                           \
    BARRIER();                                                                  \
  }

  #pragma unroll 1
  for(int tt = 0; tt < 64; tt++){
    LSTM_STEP(2*tt,     0)
    LSTM_STEP(2*tt + 1, 1)
  }
#undef LSTM_STEP

  // ---------------- head: z1 = [h_last, pm] @ Wd0^T + bd0 ; out = z1 @ Wd1^T + bd1 ----------------
  // h_last rows 0-7 in hbuf[0] (t=127 wrote buf 0); rows 8-15 zero.
  f32x4 hd[2];
  { f32x4 z4 = {0.f,0.f,0.f,0.f}; hd[0] = z4; hd[1] = z4; }
  #pragma unroll 2
  for(int kt=0; kt<8; kt++){
    bf16x8 a = *(const bf16x8*)&hbuf[0][kt*512 + l*32 + q*8];
    #pragma unroll
    for(int n=0;n<2;n++){
      int cc = w*32 + n*16 + l;
      const float* p = Wd0 + cc*268 + kt*32 + q*8;
      bf16x8 b;
      #pragma unroll
      for(int j=0;j<8;j++) b[j] = (__bf16)p[j];
      hd[n] = MFMA(a, b, hd[n]);
    }
  }
  { // K-tile 8: pm (k=256..267); only rows l<8 are real
    bf16x8 a;
    #pragma unroll
    for(int j=0;j<8;j++){
      int k2 = q*8 + j;
      a[j] = (__bf16)((l < 8 && k2 < 12) ? pm[(size_t)(wgb + l)*12 + k2] : 0.0f);
    }
    #pragma unroll
    for(int n=0;n<2;n++){
      int cc = w*32 + n*16 + l;
      bf16x8 b;
      #pragma unroll
      for(int j=0;j<8;j++){
        int k2 = q*8 + j;
        b[j] = (__bf16)((k2 < 12) ? Wd0[cc*268 + 256 + k2] : 0.0f);
      }
      hd[n] = MFMA(a, b, hd[n]);
    }
  }
  float* z1 = (float*)wlds;   // wlds reads all precede the loop-final barrier
  #pragma unroll
  for(int n=0;n<2;n++){
    int cc = w*32 + n*16 + l;
    float bb = bd0[cc];
    #pragma unroll
    for(int i=0;i<4;i++) z1[(q*4 + i)*264 + cc] = hd[n][i] + bb;
  }
  __syncthreads();
  if(tid < 256){
    int row = tid >> 5, seg = tid & 31;   // rows 0-7 x 32 segments
    const float* zr = &z1[row*264 + seg*8];
    const float* wr = Wd1 + seg*8;
    float s = 0.0f;
    #pragma unroll
    for(int j=0;j<8;j++) s += zr[j] * wr[j];
    s += __shfl_xor(s, 1);
    s += __shfl_xor(s, 2);
    s += __shfl_xor(s, 4);
    s += __shfl_xor(s, 8);
    s += __shfl_xor(s, 16);
    if(seg == 0) out[wgb + row] = s + bd1[0];
  }
}

extern "C" void kernel_launch(void* const* d_in, const int* in_sizes, int n_in,
                              void* d_out, int out_size, void* d_ws, size_t ws_size,
                              hipStream_t stream) {
  const float* x       = (const float*)d_in[0];
  const float* latlons = (const float*)d_in[1];
  const float* yearly  = (const float*)d_in[2];
  const float* pm      = (const float*)d_in[3];
  const float* Wf_i    = (const float*)d_in[4];
  const float* Wf_h    = (const float*)d_in[5];
  const float* bf_h    = (const float*)d_in[6];
  const float* Wu      = (const float*)d_in[7];
  const float* bu      = (const float*)d_in[8];
  const float* Wg_i    = (const float*)d_in[9];
  const float* Wg_h    = (const float*)d_in[10];
  const float* bg_h    = (const float*)d_in[11];
  const float* Wo_i    = (const float*)d_in[12];
  const float* Wo_h    = (const float*)d_in[13];
  const float* bo_h    = (const float*)d_in[14];
  const float* Wd0     = (const float*)d_in[15];
  const float* bd0     = (const float*)d_in[16];
  const float* Wd1     = (const float*)d_in[17];
  const float* bd1     = (const float*)d_in[18];

  ealstm_kernel<<<dim3(256), dim3(512), 0, stream>>>(
      x, latlons, yearly, pm,
      Wf_i, Wf_h, bf_h, Wu, bu,
      Wg_i, Wg_h, bg_h, Wo_i, Wo_h, bo_h,
      Wd0, bd0, Wd1, bd1,
      (float*)d_out);
}